// Round 4
// baseline (171.527 us; speedup 1.0000x reference)
//
#include <hip/hip_runtime.h>
#include <hip/hip_bf16.h>

#define T_LEN 28
#define EMB   28
#define HID   256
#define NOUT  10
#define BATCH 32768

typedef _Float16 f16x8 __attribute__((ext_vector_type(8)));
typedef _Float16 f16x4 __attribute__((ext_vector_type(4)));
typedef float    f32x4 __attribute__((ext_vector_type(4)));

// Re-layout W1/W2 into fp16 MFMA A-operand fragments.
// W2A: [jt(16)][kb(8)][lane(64)][i(8)] -> A[j][k], j = jt*16+(l&15), k = kb*32+(l>>4)*8+i
// W1A: [jt(16)][lane(64)][i(8)]        -> A[j][e], e = (l>>4)*8+i
//      e==28 carries the fused bias (b1+b2), matched by B[28][i] = 1.0; e>28 zero.
__global__ __launch_bounds__(256) void prep_kernel(
    const float* __restrict__ W1, const float* __restrict__ W2,
    const float* __restrict__ b1, const float* __restrict__ b2,
    _Float16* __restrict__ W2A, _Float16* __restrict__ W1A) {
    int idx = blockIdx.x * 256 + threadIdx.x;
    if (idx < 65536) {
        int i  = idx & 7;
        int l  = (idx >> 3) & 63;
        int kb = (idx >> 9) & 7;
        int jt = idx >> 12;
        int j  = jt * 16 + (l & 15);
        int k  = kb * 32 + (l >> 4) * 8 + i;
        W2A[idx] = (_Float16)W2[j * HID + k];
    }
    if (idx < 8192) {
        int i  = idx & 7;
        int l  = (idx >> 3) & 63;
        int jt = idx >> 9;
        int j  = jt * 16 + (l & 15);
        int k  = (l >> 4) * 8 + i;
        float v = (k < EMB) ? W1[j * EMB + k] : (k == EMB ? (b1[j] + b2[j]) : 0.f);
        W1A[idx] = (_Float16)v;
    }
}

// Block = 32 batch rows = two 16-row streams (A: 0-15, B: 16-31), 256 thr = 4 waves.
// Wave owns 64 feature cols (4 j-tiles). Dual-stream software pipeline:
//   phase1: MFMA_A(t)  || tanh_B(t-1)+write hB   ; barrier
//   phase2: MFMA_B(t)  || tanh_A(t)+write hA     ; barrier
// h LDS k-major: chunk c (k=c*8..c*8+7) at c*256 + row*16; B-frag read = base + l*16 + kb*1024.
// x B-frags loaded per step straight from global (all waves same addrs -> L1 hits).
__global__ __launch_bounds__(256, 2) void rnn_kernel(
    const float* __restrict__ seq,
    const _Float16* __restrict__ W2A,
    const _Float16* __restrict__ W1A,
    const float* __restrict__ W3,
    const float* __restrict__ b3,
    float* __restrict__ out)
{
    __shared__ __align__(16) char hls[2][8192];   // [0]=hA, [1]=hB

    const int tid = threadIdx.x;
    const int l   = tid & 63;
    const int wv  = tid >> 6;          // 0..3
    const int lr  = l & 15;
    const int lg  = l >> 4;
    const int r0  = blockIdx.x * 32;

    // W2/W1 A-fragments: 4 j-tiles (jt = wv*4 + a)
    f16x8 w2f[4][8];
#pragma unroll
    for (int a = 0; a < 4; ++a)
#pragma unroll
        for (int kb = 0; kb < 8; ++kb)
            w2f[a][kb] = *(const f16x8*)(W2A + ((((wv * 4 + a) * 8 + kb) * 64 + l) * 8));
    f16x8 w1f[4];
#pragma unroll
    for (int a = 0; a < 4; ++a)
        w1f[a] = *(const f16x8*)(W1A + (((wv * 4 + a) * 64 + l) * 8));

    // LDS write byte-offsets for this thread's 4 C-tiles (8B f16x4 each)
    int wOff[4];
#pragma unroll
    for (int a = 0; a < 4; ++a)
        wOff[a] = ((((wv * 4 + a) * 2 + (lg >> 1)) * 16) + lr) * 16 + (lg & 1) * 8;

    const float* rowA = seq + (size_t)(r0 + lr) * (T_LEN * EMB);
    const float* rowB = seq + (size_t)(r0 + 16 + lr) * (T_LEN * EMB);

    auto load_x = [&](const float* rowp, int t) -> f16x8 {
        const float* sp = rowp + t * EMB + lg * 8;
        f32x4 f0 = *(const f32x4*)sp;
        f32x4 f1 = (f32x4){1.f, 0.f, 0.f, 0.f};      // e=28 bias slot, e>28 zero
        if (lg < 3) f1 = *(const f32x4*)(sp + 4);
        f16x8 v;
#pragma unroll
        for (int q = 0; q < 4; ++q) { v[q] = (_Float16)f0[q]; v[4 + q] = (_Float16)f1[q]; }
        return v;
    };

    auto tanh4 = [&](const f32x4& a4) -> f16x4 {
        f16x4 hv;
#pragma unroll
        for (int r = 0; r < 4; ++r) {
            float e  = __builtin_amdgcn_exp2f(2.8853900817779268f * a4[r]);  // e^(2y)
            float rc = __builtin_amdgcn_rcpf(e + 1.f);
            hv[r] = (_Float16)__builtin_fmaf(-2.f, rc, 1.f);
        }
        return hv;
    };

    const f32x4 z = (f32x4){0.f, 0.f, 0.f, 0.f};
    f32x4 accA[4], accB[4];

    // MFMA(this stream) interleaved with tanh+store of the OTHER stream's pending acc.
    auto do_phase = [&](f32x4 (&acc)[4], f32x4 (&accPrev)[4],
                        const char* rbase, char* wbase, const f16x8& xf) {
        f16x8 hf[8];
#pragma unroll
        for (int kb = 0; kb < 8; ++kb)
            hf[kb] = *(const f16x8*)(rbase + kb * 1024);
#pragma unroll
        for (int kb = 0; kb < 8; ++kb) {
#pragma unroll
            for (int a = 0; a < 4; ++a)
                acc[a] = __builtin_amdgcn_mfma_f32_16x16x32_f16(
                             w2f[a][kb], hf[kb], (kb == 0) ? z : acc[a], 0, 0, 0);
            if (kb & 1) {                      // tanh one tile of the other stream
                int a2 = kb >> 1;
                *(f16x4*)(wbase + wOff[a2]) = tanh4(accPrev[a2]);
            }
        }
#pragma unroll
        for (int a = 0; a < 4; ++a)            // x projection last (hides global latency)
            acc[a] = __builtin_amdgcn_mfma_f32_16x16x32_f16(w1f[a], xf, acc[a], 0, 0, 0);
    };

    // ---- t = 0 prologue: x-only for both streams, tanh_A(0) -> hA ----
    {
        f16x8 xA = load_x(rowA, 0);
        f16x8 xB = load_x(rowB, 0);
#pragma unroll
        for (int a = 0; a < 4; ++a) {
            accA[a] = __builtin_amdgcn_mfma_f32_16x16x32_f16(w1f[a], xA, z, 0, 0, 0);
            accB[a] = __builtin_amdgcn_mfma_f32_16x16x32_f16(w1f[a], xB, z, 0, 0, 0);
        }
#pragma unroll
        for (int a = 0; a < 4; ++a)
            *(f16x4*)(hls[0] + wOff[a]) = tanh4(accA[a]);
    }
    __syncthreads();   // hA(0) visible

    for (int t = 1; t < T_LEN; ++t) {
        f16x8 xA = load_x(rowA, t);
        f16x8 xB = load_x(rowB, t);

        // phase 1: accA(t) = W2*hA(t-1) + W1*xA  ||  tanh_B(t-1) -> hB
        do_phase(accA, accB, hls[0] + l * 16, hls[1], xA);
        __syncthreads();   // hB(t-1) visible; hA reads done

        // phase 2: accB(t) = W2*hB(t-1) + W1*xB  ||  tanh_A(t) -> hA
        do_phase(accB, accA, hls[1] + l * 16, hls[0], xB);
        __syncthreads();   // hA(t) visible; hB reads done
    }

    // epilogue: tanh_B(T-1) -> hB
#pragma unroll
    for (int a = 0; a < 4; ++a)
        *(f16x4*)(hls[1] + wOff[a]) = tanh4(accB[a]);
    __syncthreads();

    // ---- head: out = h @ W3^T + b3 over 32 rows ----
    for (int idx = tid; idx < 32 * NOUT; idx += 256) {
        int i = idx / NOUT;
        int o = idx - i * NOUT;
        const char* hb = hls[i >> 4];
        int ii = i & 15;
        float s = b3[o];
#pragma unroll
        for (int c = 0; c < 32; ++c) {
            f16x8 hv  = *(const f16x8*)(hb + c * 256 + ii * 16);
            f32x4 w0  = *(const f32x4*)(W3 + o * HID + c * 8);
            f32x4 w1v = *(const f32x4*)(W3 + o * HID + c * 8 + 4);
#pragma unroll
            for (int q = 0; q < 4; ++q)
                s += (float)hv[q] * w0[q] + (float)hv[4 + q] * w1v[q];
        }
        out[(size_t)(r0 + i) * NOUT + o] = s;
    }
}

extern "C" void kernel_launch(void* const* d_in, const int* in_sizes, int n_in,
                              void* d_out, int out_size, void* d_ws, size_t ws_size,
                              hipStream_t stream) {
    const float* seq = (const float*)d_in[0];
    const float* W1  = (const float*)d_in[1];
    const float* b1  = (const float*)d_in[2];
    const float* W2  = (const float*)d_in[3];
    const float* b2  = (const float*)d_in[4];
    const float* W3  = (const float*)d_in[5];
    const float* b3  = (const float*)d_in[6];
    float* outp = (float*)d_out;

    _Float16* W2A = (_Float16*)d_ws;
    _Float16* W1A = (_Float16*)((char*)d_ws + 65536 * sizeof(_Float16));

    prep_kernel<<<256, 256, 0, stream>>>(W1, W2, b1, b2, W2A, W1A);
    rnn_kernel<<<BATCH / 32, 256, 0, stream>>>(seq, W2A, W1A, W3, b3, outp);
}